// Round 8
// baseline (234.466 us; speedup 1.0000x reference)
//
#include <hip/hip_runtime.h>
#include <hip/hip_bf16.h>
#include <math.h>

// Problem constants
#define J   21
#define NH  7
#define H   4
#define HD  64
#define ALPHA 0.2f

// LDS strides (in elements)
#define HPS  264   // hp_bf row stride (shorts): k-contiguous (256+8 pad)
#define JPA  40    // attn_bf / x_bf row stride (shorts)
#define JPT  24    // h_t / h2_t row stride (shorts); j 21..23 zeroed; quad3 b128 reads overlap
                   // the next row (finite) — A-side k>=21 is exact zero so products vanish;
                   // the very last h_t row spills into the zeroed tail pad.
#define F12S 24    // f1/f2 per-head stride (floats)

// LDS map (floats), total 7932 f = 31728 B:
//   [0,2904)      hp_bf[22][HPS] shorts (s4 out / s5 A); xs_raw[147] fp32 overlay (s0/s1b);
//                 attn2_bf @ short-off 96 = floats [48,400) (s7 out / s8 A)
//   [2904,4664)   attn_bf[4][22][JPA] shorts (s3 out / s4 B); x_bf bf16 overlay (s0/s1 A)
//   [4664,4856)   f1[4][F12S], f2[4][F12S] (s1b out / s3 in); f1o@4664, f2o@4688 overlay (s5 out / s7 in)
//   [4856,7928)   h_t[256][JPT] shorts (s1 out / s4 A); h2_t[64][JPT] overlay @ 6300 (s5 out / s8 B)
//   [7928,7932)   tail pad — zeroed in s0 (quad3 spillover of last h_t row)
#define LDS_FLOATS 7932

typedef __attribute__((ext_vector_type(8))) short short8;
typedef __attribute__((ext_vector_type(4))) float floatx4;

static __device__ __forceinline__ short f2bf(float f) {          // RNE (preconv only)
    __hip_bfloat16 h = __float2bfloat16(f);
    return __builtin_bit_cast(short, h);
}
static __device__ __forceinline__ short hi16(float f) {          // truncating bf16 (cheap)
    return (short)(__builtin_bit_cast(unsigned, f) >> 16);
}
static __device__ __forceinline__ unsigned pack2hi(float lo, float hi) {
    // D = [hi16(hi) : hi16(lo)] in one v_perm_b32
    return __builtin_amdgcn_perm(__builtin_bit_cast(unsigned, hi),
                                 __builtin_bit_cast(unsigned, lo), 0x07060302u);
}
static __device__ __forceinline__ float elu(float a) {
    return (a > 0.f) ? a : (__expf(a) - 1.f);
}

// ---- pre-kernel: bf16 weight tables + fused-dot tables ----
// ws shorts: [0,16384)      WoT[n=64][k=256] = bf(Wo[k][n])
//            [16384,18432)  WhT[(h*64+d)][8] : n<7 -> bf(Wh[h][n][d]), n=7 -> 0
//            [18432,18560)  wha[h][2][8] fp32 : wha[h][s][n] = sum_d Wh[h][n][d]*ah[h][s*64+d]
//            [18560,22656)  WoaT[s=16][k=256] : s<2 -> bf(sum_d Wo[k][d]*ao[s*64+d]), else 0
__global__ void preconv(const float* __restrict__ Wo, const float* __restrict__ Wh,
                        const float* __restrict__ ah, const float* __restrict__ ao,
                        short* __restrict__ ws) {
    int t = blockIdx.x * 256 + threadIdx.x;
    if (t < 16384) {
        int n = t >> 8, k = t & 255;
        ws[t] = f2bf(Wo[k * HD + n]);
    } else if (t < 18432) {
        int i = t - 16384;
        int hh = i >> 9, d = (i >> 3) & 63, n = i & 7;
        ws[t] = (n < 7) ? f2bf(Wh[(hh * NH + n) * HD + d]) : (short)0;
    } else if (t < 18496) {
        int i = t - 18432;                 // 0..63
        int hh = i >> 4, s = (i >> 3) & 1, n = i & 7;
        float acc = 0.f;
        if (n < 7) {
            for (int d = 0; d < HD; d++)
                acc += Wh[(hh * NH + n) * HD + d] * ah[hh * 2 * HD + s * HD + d];
        }
        ((float*)(ws + 18432))[i] = acc;
    } else if (t < 22592) {
        int i = t - 18496;                 // 0..4095
        int s = i >> 8, k = i & 255;
        short v = 0;
        if (s < 2) {
            float acc = 0.f;
            for (int d = 0; d < HD; d++)
                acc += Wo[k * HD + d] * ao[s * HD + d];
            v = f2bf(acc);
        }
        ws[18560 + i] = v;
    }
}

__global__ __launch_bounds__(256, 4)
void gat_kernel(const float* __restrict__ inp,
                const short* __restrict__ ws,   // WoT + WhT + wha + WoaT
                float* __restrict__ out)
{
    __shared__ __align__(16) float smem[LDS_FLOATS];
    short* hp_bf    = (short*)smem;                 // [22][HPS]
    short* attn2_bf = (short*)smem + 96;            // [22][32] floats [48,400)
    short* attn_bf  = (short*)(smem + 2904);        // [4][22][JPA]
    float* f1       = smem + 4664;                  // [4][F12S]
    float* f2       = smem + 4760;
    float* f1o      = smem + 4664;                  // overlay (f1/f2 dead post-s3)
    float* f2o      = smem + 4688;
    short* h_t      = (short*)(smem + 4856);        // [256][JPT]
    short* h2_t     = (short*)(smem + 6300);        // [64][JPT] (overlays dead h_t)

    const short* WoT  = ws;
    const short* WhT  = ws + 16384;
    const float* whaF = (const float*)(ws + 18432);
    const short* WoaT = ws + 18560;

    const int t    = threadIdx.x;
    const int w    = t >> 6;          // wave = head = tile index
    const int lane = t & 63;
    const int quad = lane >> 4;
    const int col  = lane & 15;
    const int rc   = (16 + col < 21) ? (16 + col) : 21;   // clamped M1 A-row (row 21 = zeros)

    const size_t pair = blockIdx.x;
    const float* ip = inp + pair * (size_t)(J * NH);

    // ---- stage 0: zero x_bf region + tail; scatter inputs (raw fp32 + bf16 A-layout) ----
    for (int e = t; e < 440; e += 256) smem[2904 + e] = 0.f;
    if (t < 4) smem[7928 + t] = 0.f;   // tail pad: stage-4 quad3 A-read of last h_t row
    __syncthreads();
    if (t < J * NH) {
        float v = ip[t];
        int j, k;
        if (t < 63)       { j = t / 3;        k = t % 3; }
        else if (t < 126) { j = (t - 63) / 3; k = 3 + (t - 63) % 3; }
        else              { j = t - 126;      k = 6; }
        ((short*)(smem + 2904))[j * JPA + k] = hi16(v);   // x_bf
        smem[t] = v;                                      // xs_raw (hp region, dead until s4)
    }
    __syncthreads();

    // ---- stage 1 (MFMA): h = x[21x7pad32] @ Wh_head[7x64] -> h_t bf16 (B-layout, b64-packed);
    //      1b: f1/f2 = x @ wha (fp32) ----
    {
        const short* x_bf = (const short*)(smem + 2904);
        short8 xa0 = *(const short8*)(x_bf + col * JPA + quad * 8);
        short8 xa1 = *(const short8*)(x_bf + rc  * JPA + quad * 8);
        #pragma unroll
        for (int nt = 0; nt < 4; nt++) {
            short8 b = *(const short8*)(WhT + ((w * 64 + nt * 16 + col) << 3) + quad * 8);
            floatx4 z = {0.f, 0.f, 0.f, 0.f};
            floatx4 c0 = __builtin_amdgcn_mfma_f32_16x16x32_bf16(xa0, b, z, 0, 0, 0);
            floatx4 c1 = __builtin_amdgcn_mfma_f32_16x16x32_bf16(xa1, b, z, 0, 0, 0);
            short* cb = h_t + (w * 64 + nt * 16 + col) * JPT;
            *(uint2*)(cb + quad * 4) =
                make_uint2(pack2hi(c0[0], c0[1]), pack2hi(c0[2], c0[3]));
            if (quad == 0)
                *(uint2*)(cb + 16) =
                    make_uint2(pack2hi(c1[0], c1[1]), pack2hi(c1[2], c1[3]));
            else if (quad == 1)
                *(uint2*)(cb + 20) = make_uint2(pack2hi(c1[0], 0.f), 0u);  // j=20 + zero pad 21..23
        }
        if (t < 84) {
            int hh = t / 21, j = t - hh * 21;
            const float* xr = smem;    // xs_raw
            float x0 = xr[j*3+0], x1 = xr[j*3+1], x2 = xr[j*3+2];
            float x3 = xr[63+j*3+0], x4 = xr[63+j*3+1], x5 = xr[63+j*3+2];
            float x6 = xr[126+j];
            const float* wp = whaF + hh * 16;
            f1[hh * F12S + j] = x0*wp[0] + x1*wp[1] + x2*wp[2] + x3*wp[3]
                              + x4*wp[4] + x5*wp[5] + x6*wp[6];
            f2[hh * F12S + j] = x0*wp[8] + x1*wp[9] + x2*wp[10] + x3*wp[11]
                              + x4*wp[12] + x5*wp[13] + x6*wp[14];
        }
    }
    __syncthreads();

    // ---- stage 3: attn rows = softmax_j( leaky_relu(f1[i]+f2[j]) ) -> bf16; row 21 zeroed ----
    if (t < H * 22) {
        int hh = t / 22, i = t % 22;
        unsigned* rowp = (unsigned*)(attn_bf + (hh * 22 + i) * JPA);
        if (i < J) {
            float fi = f1[hh * F12S + i];
            const float* f2r = f2 + hh * F12S;
            float ev[J];
            float m = -1e30f;
            #pragma unroll
            for (int c4 = 0; c4 < 5; c4++) {
                float4 fv = ((const float4*)f2r)[c4];
                float e;
                e = fi + fv.x; e = (e >= 0.f) ? e : ALPHA * e; ev[c4*4+0] = e; m = fmaxf(m, e);
                e = fi + fv.y; e = (e >= 0.f) ? e : ALPHA * e; ev[c4*4+1] = e; m = fmaxf(m, e);
                e = fi + fv.z; e = (e >= 0.f) ? e : ALPHA * e; ev[c4*4+2] = e; m = fmaxf(m, e);
                e = fi + fv.w; e = (e >= 0.f) ? e : ALPHA * e; ev[c4*4+3] = e; m = fmaxf(m, e);
            }
            { float e = fi + f2r[20]; e = (e >= 0.f) ? e : ALPHA * e; ev[20] = e; m = fmaxf(m, e); }
            float ssum = 0.f;
            #pragma unroll
            for (int j = 0; j < J; j++) { float ex = __expf(ev[j] - m); ev[j] = ex; ssum += ex; }
            float inv = 1.f / ssum;
            #pragma unroll
            for (int k = 0; k < 10; k++)
                rowp[k] = pack2hi(ev[2*k] * inv, ev[2*k+1] * inv);
            rowp[10] = pack2hi(ev[20] * inv, 0.f);
            #pragma unroll
            for (int k = 11; k < 16; k++) rowp[k] = 0;
        } else {
            #pragma unroll
            for (int k = 0; k < 16; k++) rowp[k] = 0;
        }
    }
    __syncthreads();

    // ---- stage 4 (MFMA, transposed): hp^T[d][m] = h_t(d-rows) @ attn^T, ELU ->
    //      packed b64 stores into hp_bf[m][k] (k-contiguous). hp row 21 = zeros for free
    //      (attn row 21 is zeroed; m>21 lanes masked). ----
    {
        short8 bb0 = *(const short8*)(attn_bf + (w * 22 + col) * JPA + quad * 8);
        const int am  = 16 + col;
        const int amc = (am < 21) ? am : 21;          // clamp reads; row 21 = zeros
        short8 bb1 = *(const short8*)(attn_bf + (w * 22 + amc) * JPA + quad * 8);
        #pragma unroll
        for (int dt = 0; dt < 4; dt++) {
            short8 a = *(const short8*)(h_t + (w * 64 + dt * 16 + col) * JPT + quad * 8);
            floatx4 z = {0.f, 0.f, 0.f, 0.f};
            floatx4 c0 = __builtin_amdgcn_mfma_f32_16x16x32_bf16(a, bb0, z, 0, 0, 0);
            floatx4 c1 = __builtin_amdgcn_mfma_f32_16x16x32_bf16(a, bb1, z, 0, 0, 0);
            *(uint2*)(hp_bf + col * HPS + w * 64 + dt * 16 + quad * 4) =
                make_uint2(pack2hi(elu(c0[0]), elu(c0[1])),
                           pack2hi(elu(c0[2]), elu(c0[3])));
            if (am <= 21) {
                *(uint2*)(hp_bf + am * HPS + w * 64 + dt * 16 + quad * 4) =
                    make_uint2(pack2hi(elu(c1[0]), elu(c1[1])),
                               pack2hi(elu(c1[2]), elu(c1[3])));
            }
        }
    }
    __syncthreads();

    // ---- stage 5 (MFMA): h2 = hp[21x256] @ Wo[256x64] -> h2_t bf16 (b64-packed);
    //      wave 0 additionally computes f1o/f2o = hp @ WoaT (fused h2.ao) ----
    {
        floatx4 d0 = {0,0,0,0}, d1 = {0,0,0,0};
        #pragma unroll
        for (int s = 0; s < 8; s++) {
            short8 a0 = *(const short8*)(hp_bf + col * HPS + s * 32 + quad * 8);
            short8 a1 = *(const short8*)(hp_bf + rc  * HPS + s * 32 + quad * 8);
            short8 b  = *(const short8*)(WoT + (w * 16 + col) * 256 + s * 32 + quad * 8);
            d0 = __builtin_amdgcn_mfma_f32_16x16x32_bf16(a0, b, d0, 0, 0, 0);
            d1 = __builtin_amdgcn_mfma_f32_16x16x32_bf16(a1, b, d1, 0, 0, 0);
        }
        const int c = w * 16 + col;
        short* cb = h2_t + c * JPT;
        *(uint2*)(cb + quad * 4) = make_uint2(pack2hi(d0[0], d0[1]), pack2hi(d0[2], d0[3]));
        if (quad == 0)
            *(uint2*)(cb + 16) = make_uint2(pack2hi(d1[0], d1[1]), pack2hi(d1[2], d1[3]));
        else if (quad == 1)
            *(uint2*)(cb + 20) = make_uint2(pack2hi(d1[0], 0.f), 0u);

        if (w == 0) {   // wave-uniform branch: only wave 0 computes the f-tile
            floatx4 g0 = {0,0,0,0}, g1 = {0,0,0,0};
            #pragma unroll
            for (int s = 0; s < 8; s++) {
                short8 a0 = *(const short8*)(hp_bf + col * HPS + s * 32 + quad * 8);
                short8 a1 = *(const short8*)(hp_bf + rc  * HPS + s * 32 + quad * 8);
                short8 bg = *(const short8*)(WoaT + col * 256 + s * 32 + quad * 8);
                g0 = __builtin_amdgcn_mfma_f32_16x16x32_bf16(a0, bg, g0, 0, 0, 0);
                g1 = __builtin_amdgcn_mfma_f32_16x16x32_bf16(a1, bg, g1, 0, 0, 0);
            }
            if (col < 2) {
                float* fo = col ? f2o : f1o;
                #pragma unroll
                for (int r = 0; r < 4; r++) {
                    fo[quad * 4 + r] = g0[r];
                    int row1 = 16 + quad * 4 + r;
                    if (row1 < J) fo[row1] = g1[r];
                }
            }
        }
    }
    __syncthreads();

    // ---- stage 7: attn2 rows = softmax_j( leaky_relu(f1o[i]+f2o[j]) ) -> bf16; row 21 zero ----
    if (t < 22) {
        unsigned* rowp = (unsigned*)(attn2_bf + t * 32);
        if (t < J) {
            float fi = f1o[t];
            float ev[J];
            float m = -1e30f;
            #pragma unroll
            for (int c4 = 0; c4 < 5; c4++) {
                float4 fv = ((const float4*)f2o)[c4];
                float e;
                e = fi + fv.x; e = (e >= 0.f) ? e : ALPHA * e; ev[c4*4+0] = e; m = fmaxf(m, e);
                e = fi + fv.y; e = (e >= 0.f) ? e : ALPHA * e; ev[c4*4+1] = e; m = fmaxf(m, e);
                e = fi + fv.z; e = (e >= 0.f) ? e : ALPHA * e; ev[c4*4+2] = e; m = fmaxf(m, e);
                e = fi + fv.w; e = (e >= 0.f) ? e : ALPHA * e; ev[c4*4+3] = e; m = fmaxf(m, e);
            }
            { float e = fi + f2o[20]; e = (e >= 0.f) ? e : ALPHA * e; ev[20] = e; m = fmaxf(m, e); }
            float ssum = 0.f;
            #pragma unroll
            for (int j = 0; j < J; j++) { float ex = __expf(ev[j] - m); ev[j] = ex; ssum += ex; }
            float inv = 1.f / ssum;
            #pragma unroll
            for (int k = 0; k < 10; k++)
                rowp[k] = pack2hi(ev[2*k] * inv, ev[2*k+1] * inv);
            rowp[10] = pack2hi(ev[20] * inv, 0.f);
            #pragma unroll
            for (int k = 11; k < 16; k++) rowp[k] = 0;
        } else {
            #pragma unroll
            for (int k = 0; k < 16; k++) rowp[k] = 0;
        }
    }
    __syncthreads();

    // ---- stage 8 (MFMA, barrier-free): hp2 = attn2[21x21pad32] @ h2[21x64], ELU,
    //      log-softmax over d entirely in-wave; waves pair-duplicate MFMAs, split rows ----
    {
        const int mt = w & 1;
        const int rh = w >> 1;
        const int arow = mt * 16 + col;
        const int ar = (arow < 21) ? arow : 21;            // row 21 is all-zero
        short8 a = *(const short8*)(attn2_bf + ar * 32 + quad * 8);
        floatx4 acc[4];
        #pragma unroll
        for (int nt = 0; nt < 4; nt++) {
            short8 b = *(const short8*)(h2_t + (nt * 16 + col) * JPT + quad * 8);
            floatx4 z = {0,0,0,0};
            acc[nt] = __builtin_amdgcn_mfma_f32_16x16x32_bf16(a, b, z, 0, 0, 0);
        }
        float* outp = out + pair * (size_t)(J * HD);
        #pragma unroll
        for (int rr = 0; rr < 2; rr++) {
            int r = rh * 2 + rr;
            int row = mt * 16 + quad * 4 + r;
            float v0 = elu(acc[0][r]), v1 = elu(acc[1][r]);
            float v2 = elu(acc[2][r]), v3 = elu(acc[3][r]);
            float s = __expf(v0) + __expf(v1) + __expf(v2) + __expf(v3);
            s += __shfl_xor(s, 1);
            s += __shfl_xor(s, 2);
            s += __shfl_xor(s, 4);
            s += __shfl_xor(s, 8);
            float ls = __logf(s);
            if (row < J) {
                outp[row * HD +      col] = v0 - ls;
                outp[row * HD + 16 + col] = v1 - ls;
                outp[row * HD + 32 + col] = v2 - ls;
                outp[row * HD + 48 + col] = v3 - ls;
            }
        }
    }
}

extern "C" void kernel_launch(void* const* d_in, const int* in_sizes, int n_in,
                              void* d_out, int out_size, void* d_ws, size_t ws_size,
                              hipStream_t stream) {
    const float* inp = (const float*)d_in[0];
    // d_in[1] = seq_start_end (int64) — unused by the reference computation
    const float* Wh  = (const float*)d_in[2];
    const float* ah  = (const float*)d_in[3];
    const float* Wo  = (const float*)d_in[4];
    const float* ao  = (const float*)d_in[5];
    float* outp = (float*)d_out;
    short* ws   = (short*)d_ws;   // 22656 shorts = 45312 B

    hipLaunchKernelGGL(preconv, dim3(89), dim3(256), 0, stream, Wo, Wh, ah, ao, ws);

    const int pairs = in_sizes[0] / (J * NH);  // 16384
    hipLaunchKernelGGL(gat_kernel, dim3(pairs), dim3(256), 0, stream,
                       inp, (const short*)ws, outp);
}